// Round 4
// baseline (299.254 us; speedup 1.0000x reference)
//
#include <hip/hip_runtime.h>
#include <stdint.h>

#define NE 4096
#define FD 512
#define NCELLS 39
#define NPAIRS 8192

typedef __attribute__((ext_vector_type(8))) short short8;
typedef __attribute__((ext_vector_type(8))) unsigned short ushort8;
typedef __attribute__((ext_vector_type(4))) float f32x4;

__device__ __forceinline__ unsigned short f2bf(float f) {
  union { float f; uint32_t u; } v; v.f = f;
  uint32_t u = v.u;
  return (unsigned short)((u + 0x7fffu + ((u >> 16) & 1u)) >> 16);  // RNE
}
__device__ __forceinline__ float bf2f(unsigned short b) {
  return __uint_as_float(((uint32_t)b) << 16);
}

__device__ __forceinline__ void async16(const void* g, void* l) {
  __builtin_amdgcn_global_load_lds((const __attribute__((address_space(1))) void*)g,
                                   (__attribute__((address_space(3))) void*)l, 16, 0, 0);
}

// ---- kernel 1: embedding fp32 -> bf16 ----
__global__ __launch_bounds__(256) void conv_e(const float* __restrict__ E,
                                              unsigned short* __restrict__ Ebf) {
  const int i = blockIdx.x * 256 + threadIdx.x;
  const float4 v = ((const float4*)E)[i];
  ushort4 o;
  o.x = f2bf(v.x); o.y = f2bf(v.y); o.z = f2bf(v.z); o.w = f2bf(v.w);
  ((ushort4*)Ebf)[i] = o;
}

// ---- kernel 2: Wt[ci][k][n] = wl[c,n] * wl[c,k] * W[n,k], bf16, transposed ----
// Both wl factors folded here so the gemm accumulator IS U directly.
__global__ __launch_bounds__(256) void prep_w(const float* __restrict__ W,
                                              const float* __restrict__ wl,
                                              unsigned short* __restrict__ Wt) {
  __shared__ float tile[32][33];
  const int ci = blockIdx.z;
  const int tn = blockIdx.x * 32, tk = blockIdx.y * 32;
  const int tx = threadIdx.x & 31, ty = threadIdx.x >> 5;
  const float* wlr = wl + (size_t)ci * FD;
#pragma unroll
  for (int i = 0; i < 4; i++) {
    int n = tn + ty + i * 8;
    tile[ty + i * 8][tx] = W[(size_t)n * FD + tk + tx] * wlr[n];
  }
  __syncthreads();
  unsigned short* dst = Wt + (size_t)ci * FD * FD;
#pragma unroll
  for (int i = 0; i < 4; i++) {
    int kout = tk + ty + i * 8;
    dst[(size_t)kout * FD + tn + tx] = f2bf(tile[tx][ty + i * 8] * wlr[kout]);
  }
}

// ---- kernel 3: zero the output (harness poisons it; atomics accumulate into it) ----
__global__ __launch_bounds__(256) void zero_k(float* __restrict__ out) {
  const int i = blockIdx.x * 256 + threadIdx.x;
  ((float4*)out)[i] = (float4){0.f, 0.f, 0.f, 0.f};
}

// ---- kernel 4: bucket pairs by row-block (i0 >> 7), per cell ----
// word = p | (i1 << 13) | ((i0 & 127) << 25)   [13 + 12 + 7 = 32 bits]
__global__ __launch_bounds__(256) void bucket_k(const int* __restrict__ index,
                                                uint32_t* __restrict__ buckets,
                                                int* __restrict__ offs) {
  __shared__ int hist[32];
  __shared__ int base[32];
  __shared__ int cur[32];
  const int ci = blockIdx.x;
  const int t = threadIdx.x;
  if (t < 32) hist[t] = 0;
  __syncthreads();
  const int2* idx = (const int2*)index + (size_t)ci * NPAIRS;
  for (int j = t; j < NPAIRS; j += 256) {
    int2 id = idx[j];
    atomicAdd(&hist[id.x >> 7], 1);
  }
  __syncthreads();
  if (t == 0) {
    int s = 0;
    for (int b = 0; b < 32; b++) { base[b] = s; cur[b] = s; s += hist[b]; }
  }
  __syncthreads();
  if (t < 32) offs[ci * 32 + t] = base[t];
  for (int j = t; j < NPAIRS; j += 256) {
    int2 id = idx[j];
    int pos = atomicAdd(&cur[id.x >> 7], 1);
    buckets[(size_t)ci * NPAIRS + pos] =
        (uint32_t)j | ((uint32_t)id.y << 13) | ((uint32_t)(id.x & 127) << 25);
  }
}

// ---- kernel 5: fused gemm + pair-dot ----
// Main loop: m97-style 128x128 tile, BK=32, 4 waves (2x2), 4x4 MFMA 16x16x32.
// Epilogue: spill U-tile to LDS (bf16, padded stride 136), then for each pair in
// this (cell, row-block) bucket: dot 128-col slice with Ebf[i1], atomicAdd to out.
__global__ __launch_bounds__(256) void gemm_fused(const unsigned short* __restrict__ Ebf,
                                                  const unsigned short* __restrict__ Wt,
                                                  const uint32_t* __restrict__ buckets,
                                                  const int* __restrict__ offs,
                                                  float* __restrict__ out) {
  __shared__ __align__(16) unsigned short LDSbuf[128 * 136];  // 34816 B
  unsigned short* As = &LDSbuf[0];     // 128*32 during main loop
  unsigned short* Bs = &LDSbuf[4096];  // 128*32 during main loop
  unsigned short* T = &LDSbuf[0];      // 128 x 136 (epilogue, after barrier)

  const int t = threadIdx.x;
  const int ci = blockIdx.z, bx = blockIdx.x, by = blockIdx.y;
  const unsigned short* Ag = Ebf + (size_t)bx * 128 * FD;
  const unsigned short* Bg = Wt + (size_t)ci * FD * FD + (size_t)by * 128 * FD;

  f32x4 acc[4][4];
#pragma unroll
  for (int i = 0; i < 4; i++)
#pragma unroll
    for (int j = 0; j < 4; j++) acc[i][j] = (f32x4){0.f, 0.f, 0.f, 0.f};

  const int wave = t >> 6, lane = t & 63;
  const int wm = (wave & 1) * 64, wn = (wave >> 1) * 64;
  const int lr = lane & 15, lq = lane >> 4;
  const int idx0 = t, idx1 = 256 + t;
  const int r0 = idx0 >> 2, cb0 = (idx0 & 3) * 8;
  const int r1 = idx1 >> 2, cb1 = (idx1 & 3) * 8;

  for (int k0 = 0; k0 < FD; k0 += 32) {
    async16(Ag + (size_t)r0 * FD + k0 + cb0, &As[idx0 * 8]);
    async16(Ag + (size_t)r1 * FD + k0 + cb1, &As[idx1 * 8]);
    async16(Bg + (size_t)r0 * FD + k0 + cb0, &Bs[idx0 * 8]);
    async16(Bg + (size_t)r1 * FD + k0 + cb1, &Bs[idx1 * 8]);
    __syncthreads();
    short8 af[4], bq[4];
#pragma unroll
    for (int mi = 0; mi < 4; mi++) af[mi] = *(const short8*)&As[(wm + mi * 16 + lr) * 32 + lq * 8];
#pragma unroll
    for (int ni = 0; ni < 4; ni++) bq[ni] = *(const short8*)&Bs[(wn + ni * 16 + lr) * 32 + lq * 8];
#pragma unroll
    for (int mi = 0; mi < 4; mi++)
#pragma unroll
      for (int ni = 0; ni < 4; ni++)
        acc[mi][ni] = __builtin_amdgcn_mfma_f32_16x16x32_bf16(af[mi], bq[ni], acc[mi][ni], 0, 0, 0);
    __syncthreads();
  }

  // ---- spill U tile to LDS (bf16). C/D layout: col=lane&15, row=(lane>>4)*4+reg ----
#pragma unroll
  for (int mi = 0; mi < 4; mi++) {
    const int rowb = wm + mi * 16 + lq * 4;
#pragma unroll
    for (int ni = 0; ni < 4; ni++) {
      const int col = wn + ni * 16 + lr;
#pragma unroll
      for (int r = 0; r < 4; r++) T[(rowb + r) * 136 + col] = f2bf(acc[mi][ni][r]);
    }
  }
  __syncthreads();

  // ---- pair-dot epilogue: 16 lanes per pair, 4 pairs per wave-iter ----
  const int off0 = offs[ci * 32 + bx];
  const int off1 = (bx == 31) ? NPAIRS : offs[ci * 32 + bx + 1];
  const int cnt = off1 - off0;
  const uint32_t* bk = buckets + (size_t)ci * NPAIRS + off0;
  const unsigned short* Eb = Ebf + by * 128;
  float* oc = out + (size_t)ci * NPAIRS;

  for (int j0 = wave * 4; j0 < cnt; j0 += 16) {
    const int pj = j0 + lq;
    const int act = pj < cnt;
    const uint32_t w = bk[act ? pj : 0];
    const int r = w >> 25;
    const int i1 = (w >> 13) & 0xFFF;
    const int p = w & 0x1FFF;
    const ushort8 uv = *(const ushort8*)&T[r * 136 + lr * 8];
    const ushort8 ev = *(const ushort8*)(Eb + (size_t)i1 * FD + lr * 8);
    float s = 0.f;
#pragma unroll
    for (int q = 0; q < 8; q++) s += bf2f(uv[q]) * bf2f(ev[q]);
    s += __shfl_xor(s, 1, 64);
    s += __shfl_xor(s, 2, 64);
    s += __shfl_xor(s, 4, 64);
    s += __shfl_xor(s, 8, 64);
    if (act && lr == 0) atomicAdd(&oc[p], s);
  }
}

// ---- fallback (tiny workspace): direct fp32, slow but correct ----
__global__ __launch_bounds__(256) void naive_k(const float* __restrict__ emb,
                                               const int* __restrict__ index,
                                               const float* __restrict__ W,
                                               const float* __restrict__ wl,
                                               float* __restrict__ out) {
  __shared__ float bs[FD];
  __shared__ float red[256];
  const int c = blockIdx.y, p = blockIdx.x;
  const int i0 = index[((size_t)c * NPAIRS + p) * 2];
  const int i1 = index[((size_t)c * NPAIRS + p) * 2 + 1];
  const float* wlc = wl + (size_t)c * FD;
  for (int k = threadIdx.x; k < FD; k += 256) bs[k] = emb[(size_t)i1 * FD + k] * wlc[k];
  __syncthreads();
  float s = 0.f;
  for (int n = threadIdx.x; n < FD; n += 256) {
    const float* wr = W + (size_t)n * FD;
    float tacc = 0.f;
    for (int k = 0; k < FD; k++) tacc += wr[k] * bs[k];
    s += tacc * emb[(size_t)i0 * FD + n] * wlc[n];
  }
  red[threadIdx.x] = s;
  __syncthreads();
  for (int st = 128; st > 0; st >>= 1) {
    if (threadIdx.x < st) red[threadIdx.x] += red[threadIdx.x + st];
    __syncthreads();
  }
  if (threadIdx.x == 0) out[(size_t)c * NPAIRS + p] = red[0];
}

extern "C" void kernel_launch(void* const* d_in, const int* in_sizes, int n_in,
                              void* d_out, int out_size, void* d_ws, size_t ws_size,
                              hipStream_t stream) {
  const float* emb = (const float*)d_in[0];
  const int* index = (const int*)d_in[1];
  const float* Wg = (const float*)d_in[2];
  const float* wl = (const float*)d_in[3];
  float* out = (float*)d_out;

  const size_t ebytes = (size_t)NE * FD * 2;            // 4 MiB
  const size_t wtbytes = (size_t)NCELLS * FD * FD * 2;  // 19.5 MiB
  const size_t bbytes = (size_t)NCELLS * NPAIRS * 4;    // 1.25 MiB
  const size_t obytes = (size_t)NCELLS * 32 * 4;        // 5 KiB
  if (ws_size < ebytes + wtbytes + bbytes + obytes) {
    naive_k<<<dim3(NPAIRS, NCELLS), 256, 0, stream>>>(emb, index, Wg, wl, out);
    return;
  }

  unsigned short* Ebf = (unsigned short*)d_ws;
  unsigned short* Wt = (unsigned short*)((char*)d_ws + ebytes);
  uint32_t* buckets = (uint32_t*)((char*)d_ws + ebytes + wtbytes);
  int* offs = (int*)((char*)d_ws + ebytes + wtbytes + bbytes);

  conv_e<<<dim3((NE * FD / 4) / 256), 256, 0, stream>>>(emb, Ebf);
  prep_w<<<dim3(FD / 32, FD / 32, NCELLS), 256, 0, stream>>>(Wg, wl, Wt);
  bucket_k<<<dim3(NCELLS), 256, 0, stream>>>(index, buckets, offs);
  zero_k<<<dim3((NCELLS * NPAIRS / 4) / 256), 256, 0, stream>>>(out);
  gemm_fused<<<dim3(NE / 128, FD / 128, NCELLS), 256, 0, stream>>>(Ebf, Wt, buckets, offs, out);
}

// Round 6
// 243.746 us; speedup vs baseline: 1.2277x; 1.2277x over previous
//
#include <hip/hip_runtime.h>
#include <stdint.h>

#define NE 4096
#define FD 512
#define NCELLS 39
#define NPAIRS 8192

typedef __attribute__((ext_vector_type(8))) short short8;
typedef __attribute__((ext_vector_type(8))) unsigned short ushort8;
typedef __attribute__((ext_vector_type(4))) float f32x4;
typedef __attribute__((ext_vector_type(4))) unsigned int uint4v;

__device__ __forceinline__ unsigned short f2bf(float f) {
  union { float f; uint32_t u; } v; v.f = f;
  uint32_t u = v.u;
  return (unsigned short)((u + 0x7fffu + ((u >> 16) & 1u)) >> 16);  // RNE
}
__device__ __forceinline__ float bf2f(unsigned short b) {
  return __uint_as_float(((uint32_t)b) << 16);
}

__device__ __forceinline__ void async16(const void* g, void* l) {
  __builtin_amdgcn_global_load_lds((const __attribute__((address_space(1))) void*)g,
                                   (__attribute__((address_space(3))) void*)l, 16, 0, 0);
}

// ---- kernel 1: embedding fp32 -> bf16 ----
__global__ __launch_bounds__(256) void conv_e(const float* __restrict__ E,
                                              unsigned short* __restrict__ Ebf) {
  const int i = blockIdx.x * 256 + threadIdx.x;
  const float4 v = ((const float4*)E)[i];
  ushort4 o;
  o.x = f2bf(v.x); o.y = f2bf(v.y); o.z = f2bf(v.z); o.w = f2bf(v.w);
  ((ushort4*)Ebf)[i] = o;
}

// ---- kernel 2: Wt[ci][k][n] = wl[c,n] * wl[c,k] * W[n,k], bf16, transposed ----
// Both wl factors folded so the gemm accumulator IS U directly (no epilogue scale).
__global__ __launch_bounds__(256) void prep_w(const float* __restrict__ W,
                                              const float* __restrict__ wl,
                                              unsigned short* __restrict__ Wt,
                                              int c0) {
  __shared__ float tile[32][33];
  const int ci = blockIdx.z;
  const int tn = blockIdx.x * 32, tk = blockIdx.y * 32;
  const int tx = threadIdx.x & 31, ty = threadIdx.x >> 5;
  const float* wlr = wl + (size_t)(c0 + ci) * FD;
#pragma unroll
  for (int i = 0; i < 4; i++) {
    int n = tn + ty + i * 8;
    tile[ty + i * 8][tx] = W[(size_t)n * FD + tk + tx] * wlr[n];
  }
  __syncthreads();
  unsigned short* dst = Wt + (size_t)ci * FD * FD;
#pragma unroll
  for (int i = 0; i < 4; i++) {
    int kout = tk + ty + i * 8;
    dst[(size_t)kout * FD + tn + tx] = f2bf(tile[tx][ty + i * 8] * wlr[kout]);
  }
}

// ---- kernel 3: U[ci][e][k] = sum_n Ebf[e,n] * Wt[ci][k][n]  (bf16 out) ----
// m97-style: 128x128 tile, BK=32, 4 waves (2x2), each wave 4x4 MFMA 16x16x32 tiles.
__global__ __launch_bounds__(256) void gemm_k(const unsigned short* __restrict__ Ebf,
                                              const unsigned short* __restrict__ Wt,
                                              unsigned short* __restrict__ U) {
  __shared__ unsigned short As[128 * 32];
  __shared__ unsigned short Bs[128 * 32];
  const int t = threadIdx.x;
  const int ci = blockIdx.z;
  const unsigned short* Ag = Ebf + (size_t)blockIdx.x * 128 * FD;
  const unsigned short* Bg = Wt + (size_t)ci * FD * FD + (size_t)blockIdx.y * 128 * FD;

  f32x4 acc[4][4];
#pragma unroll
  for (int i = 0; i < 4; i++)
#pragma unroll
    for (int j = 0; j < 4; j++) acc[i][j] = (f32x4){0.f, 0.f, 0.f, 0.f};

  const int wave = t >> 6, lane = t & 63;
  const int wm = (wave & 1) * 64, wn = (wave >> 1) * 64;
  const int lr = lane & 15, lq = lane >> 4;
  const int idx0 = t, idx1 = 256 + t;
  const int r0 = idx0 >> 2, cb0 = (idx0 & 3) * 8;
  const int r1 = idx1 >> 2, cb1 = (idx1 & 3) * 8;

  for (int k0 = 0; k0 < FD; k0 += 32) {
    async16(Ag + (size_t)r0 * FD + k0 + cb0, &As[idx0 * 8]);
    async16(Ag + (size_t)r1 * FD + k0 + cb1, &As[idx1 * 8]);
    async16(Bg + (size_t)r0 * FD + k0 + cb0, &Bs[idx0 * 8]);
    async16(Bg + (size_t)r1 * FD + k0 + cb1, &Bs[idx1 * 8]);
    __syncthreads();
    short8 af[4], bq[4];
#pragma unroll
    for (int mi = 0; mi < 4; mi++) af[mi] = *(const short8*)&As[(wm + mi * 16 + lr) * 32 + lq * 8];
#pragma unroll
    for (int ni = 0; ni < 4; ni++) bq[ni] = *(const short8*)&Bs[(wn + ni * 16 + lr) * 32 + lq * 8];
#pragma unroll
    for (int mi = 0; mi < 4; mi++)
#pragma unroll
      for (int ni = 0; ni < 4; ni++)
        acc[mi][ni] = __builtin_amdgcn_mfma_f32_16x16x32_bf16(af[mi], bq[ni], acc[mi][ni], 0, 0, 0);
    __syncthreads();
  }

  // epilogue: store bf16.  C/D: col=lane&15, row=(lane>>4)*4+reg
  unsigned short* Up = U + (size_t)ci * NE * FD;
#pragma unroll
  for (int mi = 0; mi < 4; mi++) {
    int mbase = blockIdx.x * 128 + wm + mi * 16 + lq * 4;
#pragma unroll
    for (int ni = 0; ni < 4; ni++) {
      int n = blockIdx.y * 128 + wn + ni * 16 + lr;
#pragma unroll
      for (int r = 0; r < 4; r++) {
        Up[(size_t)(mbase + r) * FD + n] = f2bf(acc[mi][ni][r]);
      }
    }
  }
}

// ---- kernel 4: out[c,p] = sum_k U[ci,i0,k] * Ebf[i1,k] ----
// 64 lanes per pair: ONE dwordx4 load covers the full 1KB row per side.
// 8-pair batches -> 16 independent loads in flight per wave. U loads nontemporal
// (read-once stream, keep 4MB E table L2-resident).
__global__ __launch_bounds__(256) void dot_k(const unsigned short* __restrict__ U,
                                             const unsigned short* __restrict__ Ebf,
                                             const int* __restrict__ index,
                                             float* __restrict__ out,
                                             int c0) {
  const int ci = blockIdx.y;
  const int c = c0 + ci;
  const int wave = threadIdx.x >> 6, lane = threadIdx.x & 63;
  const unsigned short* Uc = U + (size_t)ci * NE * FD;
  const size_t cp = (size_t)c * NPAIRS;
  const int2* idx2 = (const int2*)index + cp;
  float* op = out + cp;
  const int pbase = (blockIdx.x * 4 + wave) * 32;

  for (int batch = 0; batch < 4; batch++) {
    const int pb = pbase + batch * 8;
    int2 id[8];
#pragma unroll
    for (int b = 0; b < 8; b++) id[b] = idx2[pb + b];
    uint4v uv[8], ev[8];
#pragma unroll
    for (int b = 0; b < 8; b++) {
      uv[b] = __builtin_nontemporal_load((const uint4v*)(Uc + (size_t)id[b].x * FD + lane * 8));
      ev[b] = *(const uint4v*)(Ebf + (size_t)id[b].y * FD + lane * 8);
    }
#pragma unroll
    for (int b = 0; b < 8; b++) {
      const ushort8 u = *(const ushort8*)&uv[b];
      const ushort8 e = *(const ushort8*)&ev[b];
      float s = 0.f;
#pragma unroll
      for (int q = 0; q < 8; q++) s += bf2f(u[q]) * bf2f(e[q]);
      s += __shfl_xor(s, 1, 64);
      s += __shfl_xor(s, 2, 64);
      s += __shfl_xor(s, 4, 64);
      s += __shfl_xor(s, 8, 64);
      s += __shfl_xor(s, 16, 64);
      s += __shfl_xor(s, 32, 64);
      if (lane == b) op[pb + b] = s;
    }
  }
}

// ---- fallback (tiny workspace): direct fp32, slow but correct ----
__global__ __launch_bounds__(256) void naive_k(const float* __restrict__ emb,
                                               const int* __restrict__ index,
                                               const float* __restrict__ W,
                                               const float* __restrict__ wl,
                                               float* __restrict__ out) {
  __shared__ float bs[FD];
  __shared__ float red[256];
  const int c = blockIdx.y, p = blockIdx.x;
  const int i0 = index[((size_t)c * NPAIRS + p) * 2];
  const int i1 = index[((size_t)c * NPAIRS + p) * 2 + 1];
  const float* wlc = wl + (size_t)c * FD;
  for (int k = threadIdx.x; k < FD; k += 256) bs[k] = emb[(size_t)i1 * FD + k] * wlc[k];
  __syncthreads();
  float s = 0.f;
  for (int n = threadIdx.x; n < FD; n += 256) {
    const float* wr = W + (size_t)n * FD;
    float tacc = 0.f;
    for (int k = 0; k < FD; k++) tacc += wr[k] * bs[k];
    s += tacc * emb[(size_t)i0 * FD + n] * wlc[n];
  }
  red[threadIdx.x] = s;
  __syncthreads();
  for (int st = 128; st > 0; st >>= 1) {
    if (threadIdx.x < st) red[threadIdx.x] += red[threadIdx.x + st];
    __syncthreads();
  }
  if (threadIdx.x == 0) out[(size_t)c * NPAIRS + p] = red[0];
}

extern "C" void kernel_launch(void* const* d_in, const int* in_sizes, int n_in,
                              void* d_out, int out_size, void* d_ws, size_t ws_size,
                              hipStream_t stream) {
  const float* emb = (const float*)d_in[0];
  const int* index = (const int*)d_in[1];
  const float* Wg = (const float*)d_in[2];
  const float* wl = (const float*)d_in[3];
  float* out = (float*)d_out;

  const size_t ebytes = (size_t)NE * FD * 2;  // 4 MiB bf16 embedding
  const size_t wtcell = (size_t)FD * FD * 2;  // 0.5 MiB per-cell Wt
  const size_t ucell = (size_t)NE * FD * 2;   // 4 MiB per-cell U
  size_t avail = ws_size > ebytes ? ws_size - ebytes : 0;
  int G = (int)(avail / (wtcell + ucell));
  if (G > NCELLS) G = NCELLS;

  if (G < 1) {
    naive_k<<<dim3(NPAIRS, NCELLS), 256, 0, stream>>>(emb, index, Wg, wl, out);
    return;
  }

  unsigned short* Ebf = (unsigned short*)d_ws;
  unsigned short* Wt = (unsigned short*)((char*)d_ws + ebytes);
  unsigned short* U = (unsigned short*)((char*)d_ws + ebytes + (size_t)G * wtcell);

  conv_e<<<dim3((NE * FD / 4) / 256), 256, 0, stream>>>(emb, Ebf);
  for (int c0 = 0; c0 < NCELLS; c0 += G) {
    int g = (NCELLS - c0 < G) ? (NCELLS - c0) : G;
    prep_w<<<dim3(FD / 32, FD / 32, g), 256, 0, stream>>>(Wg, wl, Wt, c0);
    gemm_k<<<dim3(NE / 128, FD / 128, g), 256, 0, stream>>>(Ebf, Wt, U);
    dot_k<<<dim3(NPAIRS / 128, g), 256, 0, stream>>>(U, Ebf, index, out, c0);
  }
}